// Round 3
// baseline (237.576 us; speedup 1.0000x reference)
//
#include <hip/hip_runtime.h>
#include <math.h>

#define D 64
#define K 512
#define BLOCK 256
#define ROWS 64              // rows per block (= lanes per wave)
#define KW 128               // codes per wave (K / 4 waves)
#define CH 8                 // codes per chunk (8 independent fmaf chains)
#define NPART 32

// Bit-level emulation of the harness's numpy fp32 reference (validated at
// absmax 0.0):
//   dist[i,k] = fp32( fp32(sx[i] + se[k]) - 2*dot[i,k] )
// sx/se = numpy pairwise sums (8-accumulator kernel, contraction OFF),
// dot = sequential single-accumulator fmaf chain over j=0..63 (ascending).
// argmin strict-<, first occurrence.
//
// Round-3 bottleneck was the LDS pipe: 16 ds_read_b128 per 256 FMAs =
// 1.0 B/FMA vs the 0.66 B/FMA break-even of the single per-CU LDS pipe
// (~125K LDS cyc vs 74K VALU cyc per CU -> VALUBusy 56%). This version
// feeds e through the SCALAR pipe instead: wave w owns code slice
// [w*128,(w+1)*128), so e addresses are wave-uniform -> s_load; x lives
// entirely in VGPRs (64/lane); se precomputed to workspace. The inner loop
// issues ZERO LDS and ZERO VMEM instructions - only v_fma with one SGPR
// operand (legal). Per-(row,k) arithmetic chains unchanged.

// numpy pairwise sum of v[j]*v[j], n=64; contraction OFF so each mul and
// add rounds separately, exactly like numpy's scalar kernel.
__device__ __forceinline__ float np_sumsq64(const float* v) {
#pragma clang fp contract(off)
    float r[8];
#pragma unroll
    for (int m = 0; m < 8; ++m) r[m] = v[m] * v[m];
#pragma unroll
    for (int i = 8; i < 64; i += 8) {
#pragma unroll
        for (int m = 0; m < 8; ++m) r[m] = r[m] + v[i + m] * v[i + m];
    }
    return ((r[0] + r[1]) + (r[2] + r[3])) + ((r[4] + r[5]) + (r[6] + r[7]));
}

// Precompute ||e_k||^2 (numpy-pairwise) into workspace. 512 threads total.
__global__ __launch_bounds__(64) void vq_se(
    const float* __restrict__ emb, float* __restrict__ se_ws)
{
    const int k = blockIdx.x * 64 + threadIdx.x;   // grid 8 x 64 = 512
    float er[D];
    const float4* e4 = (const float4*)(emb + (size_t)k * D);
#pragma unroll
    for (int j = 0; j < 16; ++j) {
        float4 v = e4[j];
        er[4 * j + 0] = v.x; er[4 * j + 1] = v.y;
        er[4 * j + 2] = v.z; er[4 * j + 3] = v.w;
    }
    se_ws[k] = np_sumsq64(er);
}

__global__ __launch_bounds__(BLOCK, 4) void vq_main(
    const float* __restrict__ x, const float* __restrict__ emb,
    const float* __restrict__ se_ws,
    float* __restrict__ q_out, float* __restrict__ idx_out,
    float* __restrict__ block_sums, int* __restrict__ part_hist, int N)
{
    __shared__ float2 bests[4 * ROWS];  // per-wave (d, k) candidates
    __shared__ int hist[K];

    const int tid = threadIdx.x;
    const int lane = tid & 63;
    // readfirstlane pins the wave id into an SGPR -> all e/se addressing is
    // provably wave-uniform -> s_load (SMEM pipe), not per-lane VMEM.
    const int wv = __builtin_amdgcn_readfirstlane(tid >> 6);
    const int rowbase = blockIdx.x * ROWS;
    const int row = rowbase + lane;

    for (int k2 = tid; k2 < K; k2 += BLOCK) hist[k2] = 0;

    // lane's row fully in registers (64 VGPR)
    float xr[D];
    {
        const float4* xp = (const float4*)(x + (size_t)row * D);
#pragma unroll
        for (int j = 0; j < 16; ++j) {
            float4 v = xp[j];
            xr[4 * j + 0] = v.x; xr[4 * j + 1] = v.y;
            xr[4 * j + 2] = v.z; xr[4 * j + 3] = v.w;
        }
    }
    const float sx = np_sumsq64(xr);

    float bd = INFINITY, bk = 0.f;
    const int wk = wv * KW;
    for (int ch = 0; ch < KW / CH; ++ch) {
        const int kb = wk + ch * CH;
        const float* ew = emb + (size_t)kb * D;     // wave-uniform base
        const float* sep = se_ws + kb;              // wave-uniform base
        float a[CH];
#pragma unroll
        for (int c = 0; c < CH; ++c) a[c] = 0.f;
        // 8 independent sequential ascending-j fmaf chains; e from SGPRs
#pragma unroll
        for (int jc = 0; jc < 16; ++jc) {
            const float xv0 = xr[4 * jc + 0], xv1 = xr[4 * jc + 1];
            const float xv2 = xr[4 * jc + 2], xv3 = xr[4 * jc + 3];
#pragma unroll
            for (int c = 0; c < CH; ++c) {
                const float4 ev = *(const float4*)(ew + c * D + 4 * jc);
                a[c] = fmaf(xv0, ev.x, a[c]);
                a[c] = fmaf(xv1, ev.y, a[c]);
                a[c] = fmaf(xv2, ev.z, a[c]);
                a[c] = fmaf(xv3, ev.w, a[c]);
            }
        }
#pragma unroll
        for (int c = 0; c < CH; ++c) {
            float dcur = (sx + sep[c]) - 2.0f * a[c];   // ref rounding
            if (dcur < bd) { bd = dcur; bk = (float)(kb + c); }  // first-min
        }
    }

    bests[wv * ROWS + lane] = make_float2(bd, bk);
    __syncthreads();

    if (tid < ROWS) {
        // lexicographic (d, k) over the 4 wave slices, ascending k order
        float bdd = INFINITY, bjf = 1e30f;
#pragma unroll
        for (int w = 0; w < 4; ++w) {
            float2 p = bests[w * ROWS + tid];
            if (p.x < bdd || (p.x == bdd && p.y < bjf)) { bdd = p.x; bjf = p.y; }
        }
        const int bi = (int)bjf;
        atomicAdd(&hist[bi], 1);

        const float4* ep = (const float4*)(emb + (size_t)bi * D);
        float4* qp = (float4*)(q_out + (size_t)row * D);
        float s = 0.f;
#pragma unroll
        for (int jc = 0; jc < 16; ++jc) {
            float4 e = ep[jc];
            float x0 = xr[4 * jc + 0], x1 = xr[4 * jc + 1];
            float x2 = xr[4 * jc + 2], x3 = xr[4 * jc + 3];
            float dx0 = e.x - x0, dx1 = e.y - x1;
            float dx2 = e.z - x2, dx3 = e.w - x3;
            s = fmaf(dx0, dx0, s);
            s = fmaf(dx1, dx1, s);
            s = fmaf(dx2, dx2, s);
            s = fmaf(dx3, dx3, s);
            float4 qs;  // straight-through: x + (q - x)
            qs.x = x0 + dx0; qs.y = x1 + dx1;
            qs.z = x2 + dx2; qs.w = x3 + dx3;
            qp[jc] = qs;
        }
        idx_out[row] = (float)bi;

        for (int off = 32; off; off >>= 1) s += __shfl_down(s, off, 64);
        if (tid == 0) block_sums[blockIdx.x] = s;
    }

    __syncthreads();    // wave-0 hist atomics complete before flush
    const int part = (int)(blockIdx.x & (NPART - 1));
    for (int k2 = tid; k2 < K; k2 += BLOCK) {
        int h = hist[k2];
        if (h) atomicAdd(&part_hist[part * K + k2], h);
    }
}

__global__ __launch_bounds__(512) void vq_finalize(
    const float* __restrict__ block_sums, int nblocks,
    const int* __restrict__ part_hist, float* __restrict__ out_loss,
    float* __restrict__ out_perp, float inv_nelem, float inv_rows)
{
    const int tid = threadIdx.x;
    double ls = 0.0;
    for (int i = tid; i < nblocks; i += 512) ls += (double)block_sums[i];
    int c = 0;
#pragma unroll
    for (int pp = 0; pp < NPART; ++pp) c += part_hist[pp * K + tid];  // coalesced
    double ps = 0.0;
    {
        float p = (float)c * inv_rows;          // tid < 512 == K
        ps = (double)(p * logf(p + 1e-10f));
    }
    for (int off = 32; off; off >>= 1) {
        ls += __shfl_down(ls, off, 64);
        ps += __shfl_down(ps, off, 64);
    }
    __shared__ double l8[8], p8[8];
    if ((tid & 63) == 0) { l8[tid >> 6] = ls; p8[tid >> 6] = ps; }
    __syncthreads();
    if (tid == 0) {
        double L = 0.0, P = 0.0;
#pragma unroll
        for (int w = 0; w < 8; ++w) { L += l8[w]; P += p8[w]; }
        // loss = q_latent + 0.25*e_latent; forward values identical
        *out_loss = 1.25f * (float)(L * (double)inv_nelem);
        *out_perp = expf((float)(-P));
    }
}

extern "C" void kernel_launch(void* const* d_in, const int* in_sizes, int n_in,
                              void* d_out, int out_size, void* d_ws, size_t ws_size,
                              hipStream_t stream) {
    const float* x   = (const float*)d_in[0];
    const float* emb = (const float*)d_in[1];
    const int N = in_sizes[0] / D;          // 65536 rows
    const int nblocks = N / ROWS;           // 1024

    float* out      = (float*)d_out;
    float* loss_out = out;                  // [0]
    float* q_out    = out + 1;              // [1 .. N*D]
    float* perp_out = out + 1 + (size_t)N * D;
    float* idx_out  = perp_out + 1;         // [.. + N]

    // ws: [block_sums: 1024 f32][part_hist: 32*512 i32][se: 512 f32]
    float* block_sums = (float*)d_ws;
    char*  base       = (char*)d_ws;
    int*   part_hist  = (int*)(base + (((size_t)nblocks * 4 + 255) & ~(size_t)255));
    float* se_ws      = (float*)((char*)part_hist + (size_t)NPART * K * sizeof(int));

    hipMemsetAsync(part_hist, 0, NPART * K * sizeof(int), stream);
    vq_se<<<dim3(K / 64), 64, 0, stream>>>(emb, se_ws);
    vq_main<<<nblocks, BLOCK, 0, stream>>>(x, emb, se_ws, q_out, idx_out,
                                           block_sums, part_hist, N);
    vq_finalize<<<1, 512, 0, stream>>>(block_sums, nblocks, part_hist,
                                       loss_out, perp_out,
                                       1.0f / (float)((size_t)N * D),
                                       1.0f / (float)N);
}

// Round 4
// 204.929 us; speedup vs baseline: 1.1593x; 1.1593x over previous
//
#include <hip/hip_runtime.h>
#include <math.h>

#define D 64
#define K 512
#define BLOCK 256
#define ROWS 128            // rows per block
#define NTILE 4             // code tiles of 128 (16 cg-groups x 8)
#define NPART 32

// Bit-level emulation of the harness's numpy fp32 reference (validated at
// absmax 0.0):
//   dist[i,k] = fp32( fp32(sx[i] + se[k]) - 2*dot[i,k] )
// sx/se = numpy pairwise sums (8-accumulator kernel, contraction OFF),
// dot = sequential single-accumulator fmaf chain over j=0..63 (ascending).
// argmin strict-<, first occurrence (lexicographic (d,k) merges).
//
// Round-4: round-2's 8x8 register tile was LDS-pipe bound (16 ds_read_b128
// per 256 FMAs = 196K cyc/CU = its 82 us) + 6.66M conflict cycles from the
// sx/se prologues. This version feeds e from GLOBAL via base+imm-offset
// dwordx4 (VMEM/L1 pipe, L1-resident 32KB tile, zero addr VALU) and keeps
// only x in LDS (8 reads/jc, 2-way = free): LDS 49K cyc/CU < VALU 65.5K/SIMD
// -> compute-bound. sx/se from per-lane global reads (conflict-free). The
// finalize pass runs in the last-arriving block (ticket atomic + fences):
// graph = memset + 1 kernel. Per-(row,k) arithmetic chains unchanged.

// numpy pairwise sum of v[j]*v[j], n=64; contraction OFF so each mul and
// add rounds separately, exactly like numpy's scalar kernel.
__device__ __forceinline__ float np_sumsq64(const float* v) {
#pragma clang fp contract(off)
    float r[8];
#pragma unroll
    for (int m = 0; m < 8; ++m) r[m] = v[m] * v[m];
#pragma unroll
    for (int i = 8; i < 64; i += 8) {
#pragma unroll
        for (int m = 0; m < 8; ++m) r[m] = r[m] + v[i + m] * v[i + m];
    }
    return ((r[0] + r[1]) + (r[2] + r[3])) + ((r[4] + r[5]) + (r[6] + r[7]));
}

__global__ __launch_bounds__(BLOCK, 2) void vq_fused(
    const float* __restrict__ x, const float* __restrict__ emb,
    float* __restrict__ q_out, float* __restrict__ idx_out,
    float* __restrict__ block_sums, int* __restrict__ part_hist,
    int* __restrict__ done_ctr,
    float* __restrict__ out_loss, float* __restrict__ out_perp,
    float inv_nelem, float inv_rows)
{
    // swizzled x tile: float4 index = row*16 + (jc ^ ((row>>3)&7))
    __shared__ float4 xs4[ROWS * 16];       // 32 KB
    __shared__ float sx_s[ROWS];
    __shared__ float se_s[K];               // 2 KB
    __shared__ float2 bests[4 * ROWS];      // 4 KB: per-wave per-row (d,k)
    __shared__ int hist[K];                 // 2 KB
    __shared__ float redf[BLOCK / 64];
    __shared__ double l8[BLOCK / 64], p8[BLOCK / 64];
    __shared__ int flag_s;

    const int tid = threadIdx.x;
    const int lane = tid & 63;
    const int wv = tid >> 6;
    const int rg = tid & 15;                // row-group: rows rg*8..rg*8+7
    const int cg = tid >> 4;                // code-group 0..15
    const int rowbase = blockIdx.x * ROWS;

    for (int k2 = tid; k2 < K; k2 += BLOCK) hist[k2] = 0;

    // ---- stage x tile (coalesced global -> swizzled LDS) ----
    const float4* xsrc = (const float4*)(x + (size_t)rowbase * D);
#pragma unroll
    for (int i = 0; i < (ROWS * 16) / BLOCK; ++i) {      // 8 float4/thread
        int f = tid + i * BLOCK;
        int row = f >> 4, jc = f & 15;
        xs4[row * 16 + (jc ^ ((row >> 3) & 7))] = xsrc[f];
    }

    // ---- se for all K codes (2/thread), per-lane global reads: no LDS
    // conflicts, numpy-pairwise identical ----
#pragma unroll
    for (int t = 0; t < K / BLOCK; ++t) {
        const int k0 = tid + t * BLOCK;
        float er[D];
        const float4* e4 = (const float4*)(emb + (size_t)k0 * D);
#pragma unroll
        for (int j = 0; j < 16; ++j) {
            float4 v = e4[j];
            er[4 * j + 0] = v.x; er[4 * j + 1] = v.y;
            er[4 * j + 2] = v.z; er[4 * j + 3] = v.w;
        }
        se_s[k0] = np_sumsq64(er);
    }

    // ---- sx for the block's rows (tid<128), per-lane global reads ----
    if (tid < ROWS) {
        float xr[D];
        const float4* xp = (const float4*)(x + (size_t)(rowbase + tid) * D);
#pragma unroll
        for (int j = 0; j < 16; ++j) {
            float4 v = xp[j];
            xr[4 * j + 0] = v.x; xr[4 * j + 1] = v.y;
            xr[4 * j + 2] = v.z; xr[4 * j + 3] = v.w;
        }
        sx_s[tid] = np_sumsq64(xr);
    }
    __syncthreads();

    float bd[8], bkf[8];
#pragma unroll
    for (int r = 0; r < 8; ++r) { bd[r] = INFINITY; bkf[r] = 0.f; }

    const int xbase = rg * 8;
    const int sw = rg & 7;

#pragma unroll 1
    for (int t = 0; t < NTILE; ++t) {
        const int kb = t * 128 + cg * 8;    // thread's 8 codes this tile
        const float4* ebase = (const float4*)(emb + (size_t)kb * D);

        float acc[8][8];
#pragma unroll
        for (int r = 0; r < 8; ++r)
#pragma unroll
            for (int c = 0; c < 8; ++c) acc[r][c] = 0.f;

        // x: 8 ds_read_b128 (2-way aliased = free); e: 8 global dwordx4 with
        // immediate offsets off one base (L1-resident tile, zero addr VALU).
        // Each acc is the sequential ascending-j fmaf chain.
#pragma unroll 4
        for (int jc = 0; jc < 16; ++jc) {
            float4 xa[8];
#pragma unroll
            for (int r = 0; r < 8; ++r)
                xa[r] = xs4[(xbase + r) * 16 + (jc ^ sw)];
#pragma unroll
            for (int c = 0; c < 8; ++c) {
                const float4 ev = ebase[c * 16 + jc];   // offset:c*256+jc*16
                acc[0][c] = fmaf(xa[0].x, ev.x, acc[0][c]);
                acc[1][c] = fmaf(xa[1].x, ev.x, acc[1][c]);
                acc[2][c] = fmaf(xa[2].x, ev.x, acc[2][c]);
                acc[3][c] = fmaf(xa[3].x, ev.x, acc[3][c]);
                acc[4][c] = fmaf(xa[4].x, ev.x, acc[4][c]);
                acc[5][c] = fmaf(xa[5].x, ev.x, acc[5][c]);
                acc[6][c] = fmaf(xa[6].x, ev.x, acc[6][c]);
                acc[7][c] = fmaf(xa[7].x, ev.x, acc[7][c]);
                acc[0][c] = fmaf(xa[0].y, ev.y, acc[0][c]);
                acc[1][c] = fmaf(xa[1].y, ev.y, acc[1][c]);
                acc[2][c] = fmaf(xa[2].y, ev.y, acc[2][c]);
                acc[3][c] = fmaf(xa[3].y, ev.y, acc[3][c]);
                acc[4][c] = fmaf(xa[4].y, ev.y, acc[4][c]);
                acc[5][c] = fmaf(xa[5].y, ev.y, acc[5][c]);
                acc[6][c] = fmaf(xa[6].y, ev.y, acc[6][c]);
                acc[7][c] = fmaf(xa[7].y, ev.y, acc[7][c]);
                acc[0][c] = fmaf(xa[0].z, ev.z, acc[0][c]);
                acc[1][c] = fmaf(xa[1].z, ev.z, acc[1][c]);
                acc[2][c] = fmaf(xa[2].z, ev.z, acc[2][c]);
                acc[3][c] = fmaf(xa[3].z, ev.z, acc[3][c]);
                acc[4][c] = fmaf(xa[4].z, ev.z, acc[4][c]);
                acc[5][c] = fmaf(xa[5].z, ev.z, acc[5][c]);
                acc[6][c] = fmaf(xa[6].z, ev.z, acc[6][c]);
                acc[7][c] = fmaf(xa[7].z, ev.z, acc[7][c]);
                acc[0][c] = fmaf(xa[0].w, ev.w, acc[0][c]);
                acc[1][c] = fmaf(xa[1].w, ev.w, acc[1][c]);
                acc[2][c] = fmaf(xa[2].w, ev.w, acc[2][c]);
                acc[3][c] = fmaf(xa[3].w, ev.w, acc[3][c]);
                acc[4][c] = fmaf(xa[4].w, ev.w, acc[4][c]);
                acc[5][c] = fmaf(xa[5].w, ev.w, acc[5][c]);
                acc[6][c] = fmaf(xa[6].w, ev.w, acc[6][c]);
                acc[7][c] = fmaf(xa[7].w, ev.w, acc[7][c]);
            }
        }

        // dist + running first-min (t ascending, c ascending, strict <)
        float sev[8];
#pragma unroll
        for (int c = 0; c < 8; ++c) sev[c] = se_s[kb + c];
#pragma unroll
        for (int r = 0; r < 8; ++r) {
            const float sxv = sx_s[xbase + r];
#pragma unroll
            for (int c = 0; c < 8; ++c) {
                float dcur = (sxv + sev[c]) - 2.0f * acc[r][c];  // ref rounding
                if (dcur < bd[r]) { bd[r] = dcur; bkf[r] = (float)(kb + c); }
            }
        }
    }

    // ---- in-wave lexicographic merge across the 4 cg-subgroups ----
    // lanes lane^16, lane^32 share rg (low 4 bits untouched)
#pragma unroll
    for (int off = 16; off <= 32; off <<= 1) {
#pragma unroll
        for (int r = 0; r < 8; ++r) {
            float od = __shfl_xor(bd[r], off, 64);
            float ok = __shfl_xor(bkf[r], off, 64);
            if (od < bd[r] || (od == bd[r] && ok < bkf[r])) {
                bd[r] = od; bkf[r] = ok;
            }
        }
    }
    if (lane < 16) {
#pragma unroll
        for (int r = 0; r < 8; ++r)
            bests[wv * ROWS + lane * 8 + r] = make_float2(bd[r], bkf[r]);
    }
    __syncthreads();

    // ---- per-row final merge + gather/q/loss/idx (tid < 128) ----
    float s = 0.f;
    if (tid < ROWS) {
        float bdd = INFINITY, bjf = 1e30f;
#pragma unroll
        for (int w = 0; w < 4; ++w) {
            float2 p = bests[w * ROWS + tid];
            if (p.x < bdd || (p.x == bdd && p.y < bjf)) { bdd = p.x; bjf = p.y; }
        }
        const int bi = (int)bjf;
        atomicAdd(&hist[bi], 1);

        const int rowg = rowbase + tid;
        const float4* ep = (const float4*)(emb + (size_t)bi * D);
        float4* qp = (float4*)(q_out + (size_t)rowg * D);
        const int esw = (tid >> 3) & 7;
#pragma unroll
        for (int jc = 0; jc < 16; ++jc) {
            float4 xv = xs4[tid * 16 + (jc ^ esw)];   // bit-identical x copy
            float4 e  = ep[jc];
            float dx0 = e.x - xv.x, dx1 = e.y - xv.y;
            float dx2 = e.z - xv.z, dx3 = e.w - xv.w;
            s = fmaf(dx0, dx0, s);
            s = fmaf(dx1, dx1, s);
            s = fmaf(dx2, dx2, s);
            s = fmaf(dx3, dx3, s);
            float4 qs;  // straight-through: x + (q - x)
            qs.x = xv.x + dx0; qs.y = xv.y + dx1;
            qs.z = xv.z + dx2; qs.w = xv.w + dx3;
            qp[jc] = qs;
        }
        idx_out[rowg] = (float)bi;
    }

    // ---- loss partial (inactive lanes contribute 0) ----
    for (int off = 32; off; off >>= 1) s += __shfl_down(s, off, 64);
    if (lane == 0) redf[wv] = s;
    __syncthreads();
    if (tid == 0) {
        float tsum = 0.f;
#pragma unroll
        for (int w = 0; w < BLOCK / 64; ++w) tsum += redf[w];
        block_sums[blockIdx.x] = tsum;
    }

    // ---- hist flush (NPART partials, skip zeros) ----
    const int part = (int)(blockIdx.x & (NPART - 1));
    for (int k2 = tid; k2 < K; k2 += BLOCK) {
        int h = hist[k2];
        if (h) atomicAdd(&part_hist[part * K + k2], h);
    }

    // ---- completion ticket; last-arriving block finalizes ----
    __threadfence();            // each thread: its stores/atomics visible
    __syncthreads();
    if (tid == 0) flag_s = atomicAdd(done_ctr, 1);
    __syncthreads();
    if (flag_s != (int)gridDim.x - 1) return;

    __threadfence();            // acquire side; invalidates L1
    const int nblocks = (int)gridDim.x;
    double ls = 0.0;
    for (int i = tid; i < nblocks; i += BLOCK)
        ls += (double)__hip_atomic_load(&block_sums[i], __ATOMIC_RELAXED,
                                        __HIP_MEMORY_SCOPE_AGENT);
    double ps = 0.0;
    for (int k2 = tid; k2 < K; k2 += BLOCK) {
        int c = 0;
#pragma unroll
        for (int p = 0; p < NPART; ++p)
            c += __hip_atomic_load(&part_hist[p * K + k2], __ATOMIC_RELAXED,
                                   __HIP_MEMORY_SCOPE_AGENT);
        float pv = (float)c * inv_rows;
        ps += (double)(pv * logf(pv + 1e-10f));
    }
    for (int off = 32; off; off >>= 1) {
        ls += __shfl_down(ls, off, 64);
        ps += __shfl_down(ps, off, 64);
    }
    if (lane == 0) { l8[wv] = ls; p8[wv] = ps; }
    __syncthreads();
    if (tid == 0) {
        double L = 0.0, P = 0.0;
#pragma unroll
        for (int w = 0; w < BLOCK / 64; ++w) { L += l8[w]; P += p8[w]; }
        // loss = q_latent + 0.25*e_latent; forward values identical
        *out_loss = 1.25f * (float)(L * (double)inv_nelem);
        *out_perp = expf((float)(-P));
    }
}

extern "C" void kernel_launch(void* const* d_in, const int* in_sizes, int n_in,
                              void* d_out, int out_size, void* d_ws, size_t ws_size,
                              hipStream_t stream) {
    const float* x   = (const float*)d_in[0];
    const float* emb = (const float*)d_in[1];
    const int N = in_sizes[0] / D;          // 65536 rows
    const int nblocks = N / ROWS;           // 512

    float* out      = (float*)d_out;
    float* loss_out = out;                  // [0]
    float* q_out    = out + 1;              // [1 .. N*D]
    float* perp_out = out + 1 + (size_t)N * D;
    float* idx_out  = perp_out + 1;         // [.. + N]

    // ws: [block_sums: nblocks f32 | pad to 256B][part_hist: 32*512 i32][ctr]
    float* block_sums = (float*)d_ws;
    int*   part_hist  = (int*)((char*)d_ws +
                               (((size_t)nblocks * 4 + 255) & ~(size_t)255));
    int*   done_ctr   = part_hist + (size_t)NPART * K;

    // one memset zeroes part_hist AND the ticket counter (contiguous)
    hipMemsetAsync(part_hist, 0, (size_t)NPART * K * sizeof(int) + sizeof(int),
                   stream);
    vq_fused<<<nblocks, BLOCK, 0, stream>>>(x, emb, q_out, idx_out,
                                            block_sums, part_hist, done_ctr,
                                            loss_out, perp_out,
                                            1.0f / (float)((size_t)N * D),
                                            1.0f / (float)N);
}